// Round 3
// baseline (322.103 us; speedup 1.0000x reference)
//
#include <hip/hip_runtime.h>

// GAT 2-layer fused pipeline for MI355X.
// N=50000 nodes, E=800000 edges, H=4 heads, C=64 channels, D=4 att dims.
// Inputs bf16 (runtime-detected, fp32 fallback); edge_index int32.
//
// Round-17 = r16 resubmit (container-level infra failure, no counters) + one
// hardening fix: layer-1 aggregation gather now honors the dtype flag
// (r16 read x as bf16 unconditionally, breaking the fp32 fallback).
//
// r16 structure: AGGREGATE-THEN-TRANSFORM.
//   h = x@W is linear, so sum_e w*(x_src@W) = (sum_e w*x_src)@W.
//   Per dst node aggregate softmax-weighted INPUT features per head
//   (y[n,h,:] lives in registers/LDS only), then one MFMA epilogue applies
//   the head-stacked weight W'[h*Fin+f, c] = 0.25*W[f, h*64+c] (head-mean
//   folded). hmat (25.6MB) and both nodeM transforms DELETED; per-edge
//   gather volume 512B -> 256B/128B from a 12.8/6.4MB table. y and W' are
//   fp16. Alpha path (Bsd bf16 MFMA) unchanged from r15.
//   Scatter: ushort padded CSR (6.4MB span) + 4-edge/thread ILP.

#define N_NODES 50000
#define N_EDGES 800000
#define CAP 64        // padded-CSR per-node capacity (max degree ~40 here)
#define NB_SC4 782    // ceil(N_EDGES/1024) scatter blocks (4 edges/thread)
#define NB_NODE1 782  // ceil(N_NODES/64) nodeA blocks

typedef __attribute__((ext_vector_type(8))) short short8;       // 8 bf16
typedef __attribute__((ext_vector_type(8))) _Float16 f16x8;     // 8 fp16
typedef __attribute__((ext_vector_type(4))) float f32x4;
typedef __attribute__((ext_vector_type(8))) unsigned short ushort8;

__device__ __forceinline__ float bf2f(unsigned short u){
  return __uint_as_float(((unsigned int)u) << 16);
}
__device__ __forceinline__ unsigned short f2bf(float f){
  unsigned int u = __float_as_uint(f);
  u = (u + 0x7FFFu + ((u >> 16) & 1u)) >> 16;   // round-to-nearest-even
  return (unsigned short)u;
}
__device__ __forceinline__ float ldf(const void* p, int i, bool bf){
  return bf ? bf2f(((const unsigned short*)p)[i]) : ((const float*)p)[i];
}

// ---------------- weight prep (205 blocks) + dtype flag ----------------
// Blocks 0..127: W1' stacked-f16 frags; 128..191: W2'; 192..199: Bsd1 (bf16);
// 200..203: Bsd2; 204: bias copies + flag. Dtype self-detected per block.
// Stacked weight: W'[q, c] = 0.25*W[f, h*64+c], q = h*Fin+f  (head-mean folded).
// B-frag layout (mfma 16x16x32): Wf[((nt*KT+kt)*64+lane)*8+j] =
//   W'[q = kt*32+(lane>>4)*8+j][c = nt*16+(lane&15)], NT=4.
struct SetupPtrs {
  const void *W1, *A1, *aS1, *aD1, *b1, *W2, *A2, *aS2, *aD2, *b2, *x;
};

__global__ __launch_bounds__(256) void k_setup(SetupPtrs S,
    _Float16* __restrict__ Wb1f, _Float16* __restrict__ Wb2f,
    unsigned short* __restrict__ Bsd1f, unsigned short* __restrict__ Bsd2f,
    float* __restrict__ bc1, float* __restrict__ bc2,
    int* __restrict__ flag)
{
  __shared__ int sbf;
  const int tid = threadIdx.x;
  if (tid < 64){                                  // wave 0: dtype probe
    unsigned int w = ((const unsigned int*)S.x)[tid] & 0xFFFFu;
    unsigned int e = (w >> 7) & 0xFFu;
    bool hit = (e >= 100u && e <= 135u);
    unsigned long long m = __ballot(hit);
    if (tid == 0) sbf = (__popcll(m) > 40) ? 1 : 0;
  }
  __syncthreads();
  const bool bf = (sbf != 0);
  const int bw = blockIdx.x;
  if (bw < 128){                                  // W1' (K=512, KT=16): 32768 elems
    int t = bw * 256 + tid;
    int j = t & 7, lane = (t >> 3) & 63, kt = (t >> 9) & 15, nt = t >> 13;
    int q = kt * 32 + (lane >> 4) * 8 + j;        // 0..511
    int c = nt * 16 + (lane & 15);
    int h = q >> 7, f = q & 127;
    Wb1f[t] = (_Float16)(0.25f * ldf(S.W1, f * 256 + h * 64 + c, bf));
  } else if (bw < 192){                           // W2' (K=256, KT=8): 16384 elems
    int t = (bw - 128) * 256 + tid;
    int j = t & 7, lane = (t >> 3) & 63, kt = (t >> 9) & 7, nt = t >> 12;
    int q = kt * 32 + (lane >> 4) * 8 + j;        // 0..255
    int c = nt * 16 + (lane & 15);
    int h = q >> 6, f = q & 63;
    Wb2f[t] = (_Float16)(0.25f * ldf(S.W2, f * 256 + h * 64 + c, bf));
  } else if (bw < 200){                           // Bsd1 fragments: 2048 elems (kt<4)
    int t = (bw - 192) * 256 + tid;
    int j = t & 7, lane = (t >> 3) & 63, kt = t >> 9;
    int k = kt * 32 + (lane >> 4) * 8 + j;
    int c = lane & 15;
    float v = 0.f;
    if (c < 4){
      for (int dd = 0; dd < 4; ++dd)
        v += ldf(S.A1, k * 16 + c * 4 + dd, bf) * ldf(S.aS1, c * 4 + dd, bf);
    } else if (c < 8){
      int h = c - 4;
      for (int dd = 0; dd < 4; ++dd)
        v += ldf(S.A1, k * 16 + h * 4 + dd, bf) * ldf(S.aD1, h * 4 + dd, bf);
    }
    Bsd1f[t] = f2bf(v);
  } else if (bw < 204){                           // Bsd2 fragments: 1024 elems (kt<2)
    int t = (bw - 200) * 256 + tid;
    int j = t & 7, lane = (t >> 3) & 63, kt = t >> 9;
    int k = kt * 32 + (lane >> 4) * 8 + j;
    int c = lane & 15;
    float v = 0.f;
    if (c < 4){
      for (int dd = 0; dd < 4; ++dd)
        v += ldf(S.A2, k * 16 + c * 4 + dd, bf) * ldf(S.aS2, c * 4 + dd, bf);
    } else if (c < 8){
      int h = c - 4;
      for (int dd = 0; dd < 4; ++dd)
        v += ldf(S.A2, k * 16 + h * 4 + dd, bf) * ldf(S.aD2, h * 4 + dd, bf);
    }
    Bsd2f[t] = f2bf(v);
  } else {                                        // bias copies + flag
    if (tid < 64)       bc1[tid] = ldf(S.b1, tid, bf);
    else if (tid < 128) bc2[tid - 64] = ldf(S.b2, tid - 64, bf);
    else if (tid == 128) *flag = bf ? 1 : 0;
  }
}

// ---------------- alpha transform (r15 nodeM alpha path, W part stripped) ----------------

template<int F, bool DYN>
__device__ __forceinline__ void nodeA_body(int nblk, int tid,
    const void* __restrict__ xin_, const unsigned short* __restrict__ Bsdf,
    float* __restrict__ alpha_s, float* __restrict__ alpha_d,
    const int* __restrict__ flag)
{
  const int STR = F + 8;                   // row stride in ushorts (16B pad)
  const int KT  = F / 32;
  const int CH  = F / 8;
  __shared__ unsigned short xs[64 * (F + 8)];
  const int base = nblk * 64;
  bool bf = true;
  if (DYN) bf = (*flag != 0);
  for (int v = tid; v < 64 * CH; v += 256){
    int row = v / CH, c8 = v % CH;
    int node = base + row; if (node >= N_NODES) node = N_NODES - 1;
    size_t g = (size_t)node * F + c8 * 8;
    ushort8 u;
    if (!DYN || bf){
      u = *(const ushort8*)((const unsigned short*)xin_ + g);
    } else {
      const float* xf = (const float*)xin_ + g;
      float4 f0 = *(const float4*)xf, f1 = *(const float4*)(xf + 4);
      u[0]=f2bf(f0.x); u[1]=f2bf(f0.y); u[2]=f2bf(f0.z); u[3]=f2bf(f0.w);
      u[4]=f2bf(f1.x); u[5]=f2bf(f1.y); u[6]=f2bf(f1.z); u[7]=f2bf(f1.w);
    }
    *(ushort8*)&xs[row * STR + c8 * 8] = u;
  }
  __syncthreads();

  const int wave = tid >> 6, l = tid & 63;
  const int quad = l >> 4, m = l & 15;
  const int wbase = base + wave * 16;

  f32x4 aacc = (f32x4)0.f;
  #pragma unroll
  for (int kt = 0; kt < KT; ++kt){
    short8 af = *(const short8*)&xs[(wave * 16 + m) * STR + kt * 32 + quad * 8];
    short8 sdfrag = *(const short8*)(Bsdf + ((size_t)kt * 64 + l) * 8);
    aacc = __builtin_amdgcn_mfma_f32_16x16x32_bf16(af, sdfrag, aacc, 0, 0, 0);
  }
  if (m < 8){
    float* dstp = (m < 4) ? alpha_s : alpha_d;
    int hh = m & 3;
    #pragma unroll
    for (int r = 0; r < 4; ++r){
      int node = wbase + quad * 4 + r;
      if (node < N_NODES) dstp[node * 4 + hh] = aacc[r];
    }
  }
}

// ---------------- fused padded-CSR scatter (ushort, 4-edge ILP) + layer-1 alpha ----------------
// Blocks 0..781: scatter, 4 edges/thread for memory-level parallelism.
// Blocks 782..1563: nodeA1 (independent, overlaps scatter latency).

__global__ __launch_bounds__(256) void k_scatter_nodeA1(
    const int* __restrict__ src, const int* __restrict__ dst,
    int* __restrict__ fill, unsigned short* __restrict__ csr,
    const void* __restrict__ xin_, const unsigned short* __restrict__ Bsdf,
    float* __restrict__ alpha_s, float* __restrict__ alpha_d,
    const int* __restrict__ flag)
{
  const int b = blockIdx.x, tid = threadIdx.x;
  if (b < NB_SC4){
    const int ebase = b * 1024 + tid;
    int d[4], s[4];
    #pragma unroll
    for (int i = 0; i < 4; ++i){
      int e = ebase + i * 256;
      bool ok = (e < N_EDGES);
      d[i] = ok ? dst[e] : -1;
      s[i] = ok ? src[e] : 0;
    }
    #pragma unroll
    for (int i = 0; i < 4; ++i){
      if (d[i] >= 0){
        int r = atomicAdd(&fill[d[i]], 1);
        if (r < CAP) csr[((unsigned)d[i] << 6) + r] = (unsigned short)s[i];
      }
    }
    return;
  }
  nodeA_body<128, true>(b - NB_SC4, tid, xin_, Bsdf, alpha_s, alpha_d, flag);
}

// standalone layer-2 alpha kernel (x2 is always bf16)
template<int F, bool DYN>
__global__ __launch_bounds__(256) void k_nodeA(const void* __restrict__ xin_,
    const unsigned short* __restrict__ Bsdf,
    float* __restrict__ alpha_s, float* __restrict__ alpha_d,
    const int* __restrict__ flag)
{
  nodeA_body<F, DYN>(blockIdx.x, threadIdx.x, xin_, Bsdf, alpha_s, alpha_d, flag);
}

// ---------------- weighted-feature aggregation + stacked-W MFMA epilogue ----------------
// Block = 256 thr = 4 waves, 16 dst nodes (wave w owns nodes base+4w..base+4w+3).
// Phase 1 (per node, per edge): gather x[src] (wave reads the full Fin row,
//   lane l owns NF=Fin/64 features), ex[h]=exp(leaky(as[src,h]+ad[n,h])),
//   acc[h][f] += ex*x, den[h] += ex.  All softmax state lane-redundant -> no
//   cross-lane reduction. y[n,h,f] = acc/den -> fp16 LDS tile [16][4*Fin].
// Phase 2: wave w computes output n-tile nt=w of [16 nodes]x[K=4*Fin]@W'[K,64]
//   via KT f16 MFMAs; + bias, leaky 0.1, store.
// MODE 0: layer 1 — x gather dtype per flag; out x2 bf16.
// MODE 1: layer 2 — x2 always bf16; out per flag (bf16 else fp32).

template<int NF>
__device__ __forceinline__ void edge_acc(unsigned int xv, const float4 as4,
    const float4 ad4, float den[4], float acc[4][NF])
{
  float e0 = as4.x + ad4.x; e0 = fmaxf(e0, 0.2f * e0); float w0 = __expf(e0);
  float e1 = as4.y + ad4.y; e1 = fmaxf(e1, 0.2f * e1); float w1 = __expf(e1);
  float e2 = as4.z + ad4.z; e2 = fmaxf(e2, 0.2f * e2); float w2 = __expf(e2);
  float e3 = as4.w + ad4.w; e3 = fmaxf(e3, 0.2f * e3); float w3 = __expf(e3);
  den[0] += w0; den[1] += w1; den[2] += w2; den[3] += w3;
  float lo = bf2f((unsigned short)(xv & 0xFFFFu));
  acc[0][0] += w0 * lo; acc[1][0] += w1 * lo;
  acc[2][0] += w2 * lo; acc[3][0] += w3 * lo;
  if (NF == 2){
    float hi = bf2f((unsigned short)(xv >> 16));
    acc[0][NF-1] += w0 * hi; acc[1][NF-1] += w1 * hi;
    acc[2][NF-1] += w2 * hi; acc[3][NF-1] += w3 * hi;
  }
}

// gather lane-l features of node s, packed as (up to) 2 bf16 in a dword
template<int FIN, bool BF>
__device__ __forceinline__ unsigned int ldx(const void* xg, unsigned s, int l){
  if (FIN == 128){
    if (BF) return *(const unsigned int*)((const unsigned short*)xg + (size_t)s * 128 + 2 * l);
    const float* xf = (const float*)xg + (size_t)s * 128 + 2 * l;
    return (unsigned int)f2bf(xf[0]) | ((unsigned int)f2bf(xf[1]) << 16);
  } else {
    if (BF) return (unsigned int)((const unsigned short*)xg)[(size_t)s * 64 + l];
    return (unsigned int)f2bf(((const float*)xg)[(size_t)s * 64 + l]);
  }
}

template<int FIN, bool BF, int NF, int STR>
__device__ __forceinline__ void aggr_phase1(const void* __restrict__ xg,
    const float* __restrict__ alpha_s, const float* __restrict__ alpha_d,
    const int* __restrict__ fill, const unsigned short* __restrict__ csr,
    _Float16* __restrict__ ylds, int base, int w, int l)
{
  #pragma unroll 1
  for (int r = 0; r < 4; ++r){
    const int n = base + w * 4 + r;
    const float4 ad4 = *(const float4*)(alpha_d + n * 4);
    float den[4] = {0.f, 0.f, 0.f, 0.f};
    float acc[4][NF];
    #pragma unroll
    for (int h = 0; h < 4; ++h)
      #pragma unroll
      for (int f = 0; f < NF; ++f) acc[h][f] = 0.f;

    int cnt = fill[n]; if (cnt > CAP) cnt = CAP;
    const unsigned short* cp = csr + ((unsigned)n << 6);
    int p = 0;
    for (; p + 4 <= cnt; p += 4){
      ushort4 s4 = *(const ushort4*)(cp + p);     // 8B broadcast
      const float4 a0 = *(const float4*)(alpha_s + s4.x * 4);
      const float4 a1 = *(const float4*)(alpha_s + s4.y * 4);
      const float4 a2 = *(const float4*)(alpha_s + s4.z * 4);
      const float4 a3 = *(const float4*)(alpha_s + s4.w * 4);
      unsigned int v0 = ldx<FIN, BF>(xg, s4.x, l);
      unsigned int v1 = ldx<FIN, BF>(xg, s4.y, l);
      unsigned int v2 = ldx<FIN, BF>(xg, s4.z, l);
      unsigned int v3 = ldx<FIN, BF>(xg, s4.w, l);
      edge_acc<NF>(v0, a0, ad4, den, acc);
      edge_acc<NF>(v1, a1, ad4, den, acc);
      edge_acc<NF>(v2, a2, ad4, den, acc);
      edge_acc<NF>(v3, a3, ad4, den, acc);
    }
    for (; p < cnt; ++p){
      unsigned s = cp[p];
      const float4 a0 = *(const float4*)(alpha_s + s * 4);
      unsigned int v0 = ldx<FIN, BF>(xg, s, l);
      edge_acc<NF>(v0, a0, ad4, den, acc);
    }
    const int row = w * 4 + r;
    #pragma unroll
    for (int h = 0; h < 4; ++h){
      float rh = (den[h] > 0.f) ? (1.f / den[h]) : 0.f;
      #pragma unroll
      for (int f = 0; f < NF; ++f)
        ylds[row * STR + h * FIN + NF * l + f] = (_Float16)(acc[h][f] * rh);
    }
  }
}

template<int FIN, int MODE>
__global__ __launch_bounds__(256) void k_aggrX(
    const void* __restrict__ xg,                 // [N, FIN] bf16 (or fp32 if MODE 0 && !flag)
    const float* __restrict__ alpha_s, const float* __restrict__ alpha_d,
    const int* __restrict__ fill, const unsigned short* __restrict__ csr,
    const _Float16* __restrict__ Wf,             // f16 B-frags, NT=4, KT=FIN/8
    const float* __restrict__ bias, void* __restrict__ out,
    const int* __restrict__ flag)
{
  const int K = 4 * FIN, KT = K / 32, STR = K + 8, NF = FIN / 64;
  __shared__ _Float16 ylds[16 * (4 * FIN + 8)];
  const int tid = threadIdx.x, w = tid >> 6, l = tid & 63;
  const int base = blockIdx.x * 16;               // N divisible by 16

  if (MODE == 0 && *flag == 0)
    aggr_phase1<FIN, false, NF, STR>(xg, alpha_s, alpha_d, fill, csr, ylds, base, w, l);
  else
    aggr_phase1<FIN, true,  NF, STR>(xg, alpha_s, alpha_d, fill, csr, ylds, base, w, l);
  __syncthreads();

  const int quad = l >> 4, m = l & 15;
  const int nt = w;                               // wave w -> output cols nt*16..
  f32x4 cacc = (f32x4)0.f;
  #pragma unroll
  for (int kt = 0; kt < KT; ++kt){
    f16x8 av = *(const f16x8*)&ylds[m * STR + kt * 32 + quad * 8];
    f16x8 bv = *(const f16x8*)(Wf + ((size_t)(nt * KT + kt) * 64 + l) * 8);
    cacc = __builtin_amdgcn_mfma_f32_16x16x32_f16(av, bv, cacc, 0, 0, 0);
  }
  const int c = nt * 16 + m;
  const float bs = bias[c];
  #pragma unroll
  for (int r2 = 0; r2 < 4; ++r2){
    int node = base + quad * 4 + r2;
    float v = cacc[r2] + bs;
    v = fmaxf(v, 0.1f * v);                       // post-layer leaky 0.1
    if (MODE == 0){
      ((unsigned short*)out)[(size_t)node * 64 + c] = f2bf(v);
    } else {
      if (*flag) ((unsigned short*)out)[(size_t)node * 64 + c] = f2bf(v);
      else       ((float*)out)[(size_t)node * 64 + c] = v;
    }
  }
}

// ---------------- launch ----------------

extern "C" void kernel_launch(void* const* d_in, const int* in_sizes, int n_in,
                              void* d_out, int out_size, void* d_ws, size_t ws_size,
                              hipStream_t stream)
{
  const void* x  = d_in[0];
  const int* ei  = (const int*)d_in[1];
  const int* src = ei;
  const int* dst = ei + N_EDGES;

  char* ws = (char*)d_ws;                      // footprint ~14.7 MB
  unsigned short* csr = (unsigned short*)(ws);             // [N*64] ushort padded CSR (6.4 MB)
  unsigned short* x2  = (unsigned short*)(ws + 6400000);   // [N,64] bf16 layer-1 out (6.4 MB)
  float* as_    = (float*)(ws + 12800000);     // [N,4]
  float* ad_    = (float*)(ws + 13600000);     // [N,4]
  int*   fill   = (int*)  (ws + 14400000);     // [N] scatter atomics = degree
  _Float16* Wb1f = (_Float16*)(ws + 14600000); // [32768] f16 stacked-W1 frags
  _Float16* Wb2f = (_Float16*)(ws + 14665536); // [16384] f16 stacked-W2 frags
  unsigned short* Bsd1f = (unsigned short*)(ws + 14698304);  // [2048] bf16
  unsigned short* Bsd2f = (unsigned short*)(ws + 14702400);  // [1024] bf16
  float* bc1    = (float*)(ws + 14704448);     // [64]
  float* bc2    = (float*)(ws + 14704704);     // [64]
  int*   flag   = (int*)  (ws + 14704960);     // dtype flag (1 = bf16)

  hipMemsetAsync(fill, 0, N_NODES * sizeof(int), stream);

  SetupPtrs S;
  S.W1 = d_in[2];  S.A1 = d_in[3];  S.aS1 = d_in[4];  S.aD1 = d_in[5];  S.b1 = d_in[6];
  S.W2 = d_in[7];  S.A2 = d_in[8];  S.aS2 = d_in[9];  S.aD2 = d_in[10]; S.b2 = d_in[11];
  S.x  = x;
  k_setup<<<205, 256, 0, stream>>>(S, Wb1f, Wb2f, Bsd1f, Bsd2f, bc1, bc2, flag);

  // scatter (782 blocks, 4 edges/thread) || layer-1 alpha (782 blocks)
  k_scatter_nodeA1<<<NB_SC4 + NB_NODE1, 256, 0, stream>>>(
      src, dst, fill, csr, x, Bsd1f, as_, ad_, flag);

  // layer 1: weighted-x aggregation + stacked-W1 MFMA -> x2 bf16
  k_aggrX<128, 0><<<N_NODES / 16, 256, 0, stream>>>(
      x, as_, ad_, fill, csr, Wb1f, bc1, x2, flag);

  // layer-2 alpha from x2 (always bf16)
  k_nodeA<64, false><<<NB_NODE1, 256, 0, stream>>>(x2, Bsd2f, as_, ad_, flag);

  // layer 2: aggregation + stacked-W2 MFMA -> final out
  k_aggrX<64, 1><<<N_NODES / 16, 256, 0, stream>>>(
      x2, as_, ad_, fill, csr, Wb2f, bc2, d_out, flag);
}

// Round 4
// 296.596 us; speedup vs baseline: 1.0860x; 1.0860x over previous
//
#include <hip/hip_runtime.h>

// GAT 2-layer fused pipeline for MI355X.
// N=50000 nodes, E=800000 edges, H=4 heads, C=64 channels, D=4 att dims.
// Inputs bf16 (runtime-detected, fp32 fallback); edge_index int32.
//
// Round-18 = r17 (322 us, passed) + ONE change: aggrX phase-1 lane layout.
//   r17 made every lane compute all 4 heads' softmax (4 exps/edge lane-
//   redundant) -> VALUBusy 64%, aggrX<128> = 103 us. Now: head = lane>>4,
//   sub = lane&15; each lane owns FIN/16 features (16B/8B vector gather;
//   the 4 head-groups read the same lines -> no extra HBM traffic) and
//   exactly ONE exp chain per edge. ylds content bitwise identical, MFMA
//   epilogue unchanged -> numerics identical to r17 (absmax 1.2207e-4).
//
// Structure (r16/r17): AGGREGATE-THEN-TRANSFORM.
//   sum_e w*(x_src@W) = (sum_e w*x_src)@W; per dst aggregate softmax-weighted
//   input features per head, then stacked-weight MFMA epilogue
//   W'[h*Fin+f, c] = 0.25*W[f, h*64+c] (head-mean folded). No hmat.

#define N_NODES 50000
#define N_EDGES 800000
#define CAP 64        // padded-CSR per-node capacity (max degree ~40 here)
#define NB_SC4 782    // ceil(N_EDGES/1024) scatter blocks (4 edges/thread)
#define NB_NODE1 782  // ceil(N_NODES/64) nodeA blocks

typedef __attribute__((ext_vector_type(8))) short short8;       // 8 bf16
typedef __attribute__((ext_vector_type(8))) _Float16 f16x8;     // 8 fp16
typedef __attribute__((ext_vector_type(4))) float f32x4;
typedef __attribute__((ext_vector_type(8))) unsigned short ushort8;
typedef __attribute__((ext_vector_type(4))) unsigned short us4v;

__device__ __forceinline__ float bf2f(unsigned short u){
  return __uint_as_float(((unsigned int)u) << 16);
}
__device__ __forceinline__ unsigned short f2bf(float f){
  unsigned int u = __float_as_uint(f);
  u = (u + 0x7FFFu + ((u >> 16) & 1u)) >> 16;   // round-to-nearest-even
  return (unsigned short)u;
}
__device__ __forceinline__ float ldf(const void* p, int i, bool bf){
  return bf ? bf2f(((const unsigned short*)p)[i]) : ((const float*)p)[i];
}

// ---------------- weight prep (205 blocks) + dtype flag ----------------
// Blocks 0..127: W1' stacked-f16 frags; 128..191: W2'; 192..199: Bsd1 (bf16);
// 200..203: Bsd2; 204: bias copies + flag. Dtype self-detected per block.
// Stacked weight: W'[q, c] = 0.25*W[f, h*64+c], q = h*Fin+f  (head-mean folded).
// B-frag layout (mfma 16x16x32): Wf[((nt*KT+kt)*64+lane)*8+j] =
//   W'[q = kt*32+(lane>>4)*8+j][c = nt*16+(lane&15)], NT=4.
struct SetupPtrs {
  const void *W1, *A1, *aS1, *aD1, *b1, *W2, *A2, *aS2, *aD2, *b2, *x;
};

__global__ __launch_bounds__(256) void k_setup(SetupPtrs S,
    _Float16* __restrict__ Wb1f, _Float16* __restrict__ Wb2f,
    unsigned short* __restrict__ Bsd1f, unsigned short* __restrict__ Bsd2f,
    float* __restrict__ bc1, float* __restrict__ bc2,
    int* __restrict__ flag)
{
  __shared__ int sbf;
  const int tid = threadIdx.x;
  if (tid < 64){                                  // wave 0: dtype probe
    unsigned int w = ((const unsigned int*)S.x)[tid] & 0xFFFFu;
    unsigned int e = (w >> 7) & 0xFFu;
    bool hit = (e >= 100u && e <= 135u);
    unsigned long long m = __ballot(hit);
    if (tid == 0) sbf = (__popcll(m) > 40) ? 1 : 0;
  }
  __syncthreads();
  const bool bf = (sbf != 0);
  const int bw = blockIdx.x;
  if (bw < 128){                                  // W1' (K=512, KT=16): 32768 elems
    int t = bw * 256 + tid;
    int j = t & 7, lane = (t >> 3) & 63, kt = (t >> 9) & 15, nt = t >> 13;
    int q = kt * 32 + (lane >> 4) * 8 + j;        // 0..511
    int c = nt * 16 + (lane & 15);
    int h = q >> 7, f = q & 127;
    Wb1f[t] = (_Float16)(0.25f * ldf(S.W1, f * 256 + h * 64 + c, bf));
  } else if (bw < 192){                           // W2' (K=256, KT=8): 16384 elems
    int t = (bw - 128) * 256 + tid;
    int j = t & 7, lane = (t >> 3) & 63, kt = (t >> 9) & 7, nt = t >> 12;
    int q = kt * 32 + (lane >> 4) * 8 + j;        // 0..255
    int c = nt * 16 + (lane & 15);
    int h = q >> 6, f = q & 63;
    Wb2f[t] = (_Float16)(0.25f * ldf(S.W2, f * 256 + h * 64 + c, bf));
  } else if (bw < 200){                           // Bsd1 fragments: 2048 elems (kt<4)
    int t = (bw - 192) * 256 + tid;
    int j = t & 7, lane = (t >> 3) & 63, kt = t >> 9;
    int k = kt * 32 + (lane >> 4) * 8 + j;
    int c = lane & 15;
    float v = 0.f;
    if (c < 4){
      for (int dd = 0; dd < 4; ++dd)
        v += ldf(S.A1, k * 16 + c * 4 + dd, bf) * ldf(S.aS1, c * 4 + dd, bf);
    } else if (c < 8){
      int h = c - 4;
      for (int dd = 0; dd < 4; ++dd)
        v += ldf(S.A1, k * 16 + h * 4 + dd, bf) * ldf(S.aD1, h * 4 + dd, bf);
    }
    Bsd1f[t] = f2bf(v);
  } else if (bw < 204){                           // Bsd2 fragments: 1024 elems (kt<2)
    int t = (bw - 200) * 256 + tid;
    int j = t & 7, lane = (t >> 3) & 63, kt = t >> 9;
    int k = kt * 32 + (lane >> 4) * 8 + j;
    int c = lane & 15;
    float v = 0.f;
    if (c < 4){
      for (int dd = 0; dd < 4; ++dd)
        v += ldf(S.A2, k * 16 + c * 4 + dd, bf) * ldf(S.aS2, c * 4 + dd, bf);
    } else if (c < 8){
      int h = c - 4;
      for (int dd = 0; dd < 4; ++dd)
        v += ldf(S.A2, k * 16 + h * 4 + dd, bf) * ldf(S.aD2, h * 4 + dd, bf);
    }
    Bsd2f[t] = f2bf(v);
  } else {                                        // bias copies + flag
    if (tid < 64)       bc1[tid] = ldf(S.b1, tid, bf);
    else if (tid < 128) bc2[tid - 64] = ldf(S.b2, tid - 64, bf);
    else if (tid == 128) *flag = bf ? 1 : 0;
  }
}

// ---------------- alpha transform (r15 nodeM alpha path, W part stripped) ----------------

template<int F, bool DYN>
__device__ __forceinline__ void nodeA_body(int nblk, int tid,
    const void* __restrict__ xin_, const unsigned short* __restrict__ Bsdf,
    float* __restrict__ alpha_s, float* __restrict__ alpha_d,
    const int* __restrict__ flag)
{
  const int STR = F + 8;                   // row stride in ushorts (16B pad)
  const int KT  = F / 32;
  const int CH  = F / 8;
  __shared__ unsigned short xs[64 * (F + 8)];
  const int base = nblk * 64;
  bool bf = true;
  if (DYN) bf = (*flag != 0);
  for (int v = tid; v < 64 * CH; v += 256){
    int row = v / CH, c8 = v % CH;
    int node = base + row; if (node >= N_NODES) node = N_NODES - 1;
    size_t g = (size_t)node * F + c8 * 8;
    ushort8 u;
    if (!DYN || bf){
      u = *(const ushort8*)((const unsigned short*)xin_ + g);
    } else {
      const float* xf = (const float*)xin_ + g;
      float4 f0 = *(const float4*)xf, f1 = *(const float4*)(xf + 4);
      u[0]=f2bf(f0.x); u[1]=f2bf(f0.y); u[2]=f2bf(f0.z); u[3]=f2bf(f0.w);
      u[4]=f2bf(f1.x); u[5]=f2bf(f1.y); u[6]=f2bf(f1.z); u[7]=f2bf(f1.w);
    }
    *(ushort8*)&xs[row * STR + c8 * 8] = u;
  }
  __syncthreads();

  const int wave = tid >> 6, l = tid & 63;
  const int quad = l >> 4, m = l & 15;
  const int wbase = base + wave * 16;

  f32x4 aacc = (f32x4)0.f;
  #pragma unroll
  for (int kt = 0; kt < KT; ++kt){
    short8 af = *(const short8*)&xs[(wave * 16 + m) * STR + kt * 32 + quad * 8];
    short8 sdfrag = *(const short8*)(Bsdf + ((size_t)kt * 64 + l) * 8);
    aacc = __builtin_amdgcn_mfma_f32_16x16x32_bf16(af, sdfrag, aacc, 0, 0, 0);
  }
  if (m < 8){
    float* dstp = (m < 4) ? alpha_s : alpha_d;
    int hh = m & 3;
    #pragma unroll
    for (int r = 0; r < 4; ++r){
      int node = wbase + quad * 4 + r;
      if (node < N_NODES) dstp[node * 4 + hh] = aacc[r];
    }
  }
}

// ---------------- fused padded-CSR scatter (ushort, 4-edge ILP) + layer-1 alpha ----------------
// Blocks 0..781: scatter, 4 edges/thread for memory-level parallelism.
// Blocks 782..1563: nodeA1 (independent, overlaps scatter latency).

__global__ __launch_bounds__(256) void k_scatter_nodeA1(
    const int* __restrict__ src, const int* __restrict__ dst,
    int* __restrict__ fill, unsigned short* __restrict__ csr,
    const void* __restrict__ xin_, const unsigned short* __restrict__ Bsdf,
    float* __restrict__ alpha_s, float* __restrict__ alpha_d,
    const int* __restrict__ flag)
{
  const int b = blockIdx.x, tid = threadIdx.x;
  if (b < NB_SC4){
    const int ebase = b * 1024 + tid;
    int d[4], s[4];
    #pragma unroll
    for (int i = 0; i < 4; ++i){
      int e = ebase + i * 256;
      bool ok = (e < N_EDGES);
      d[i] = ok ? dst[e] : -1;
      s[i] = ok ? src[e] : 0;
    }
    #pragma unroll
    for (int i = 0; i < 4; ++i){
      if (d[i] >= 0){
        int r = atomicAdd(&fill[d[i]], 1);
        if (r < CAP) csr[((unsigned)d[i] << 6) + r] = (unsigned short)s[i];
      }
    }
    return;
  }
  nodeA_body<128, true>(b - NB_SC4, tid, xin_, Bsdf, alpha_s, alpha_d, flag);
}

// standalone layer-2 alpha kernel (x2 is always bf16)
template<int F, bool DYN>
__global__ __launch_bounds__(256) void k_nodeA(const void* __restrict__ xin_,
    const unsigned short* __restrict__ Bsdf,
    float* __restrict__ alpha_s, float* __restrict__ alpha_d,
    const int* __restrict__ flag)
{
  nodeA_body<F, DYN>(blockIdx.x, threadIdx.x, xin_, Bsdf, alpha_s, alpha_d, flag);
}

// ---------------- weighted-feature aggregation + stacked-W MFMA epilogue ----------------
// Block = 256 thr = 4 waves, 16 dst nodes (wave w owns nodes base+4w..base+4w+3).
// Phase 1 lane layout (r18): h = l>>4, sub = l&15; lane owns NFL = FIN/16
//   features [sub*NFL .. sub*NFL+NFL) of head h. Per edge: ONE exp chain,
//   NFL fma. The 4 head-groups read the same x-row lines (coalesced; no
//   extra HBM). y[n, h*FIN + f] -> fp16 LDS tile [16][4*FIN].
// Phase 2: wave w computes output n-tile nt=w of [16 nodes]x[K=4*FIN]@W'[K,64]
//   via KT f16 MFMAs; + bias, leaky 0.1, store.
// MODE 0: layer 1 — x gather dtype per flag; out x2 bf16.
// MODE 1: layer 2 — x2 always bf16; out per flag (bf16 else fp32).

// load lane's NFL features of node s as fp32
template<int FIN, bool BF>
__device__ __forceinline__ void ldrow(const void* xg, unsigned s, int f0,
                                      float (&out)[FIN / 16])
{
  const int NFL = FIN / 16;
  if (BF){
    const unsigned short* p = (const unsigned short*)xg + (size_t)s * FIN + f0;
    if (NFL == 8){
      ushort8 u = *(const ushort8*)p;
      #pragma unroll
      for (int j = 0; j < NFL; ++j) out[j] = bf2f(u[j]);
    } else {
      us4v u = *(const us4v*)p;
      #pragma unroll
      for (int j = 0; j < NFL; ++j) out[j] = bf2f(u[j]);
    }
  } else {
    const float* p = (const float*)xg + (size_t)s * FIN + f0;
    #pragma unroll
    for (int j = 0; j < NFL; ++j) out[j] = p[j];
  }
}

template<int FIN, bool BF, int STR>
__device__ __forceinline__ void aggr_phase1(const void* __restrict__ xg,
    const float* __restrict__ alpha_s, const float* __restrict__ alpha_d,
    const int* __restrict__ fill, const unsigned short* __restrict__ csr,
    _Float16* __restrict__ ylds, int base, int w, int l)
{
  const int NFL = FIN / 16;                       // features per lane
  const int h = l >> 4, sub = l & 15, f0 = sub * NFL;
  #pragma unroll 1
  for (int r = 0; r < 4; ++r){
    const int n = base + w * 4 + r;
    const float adv = alpha_d[n * 4 + h];
    float den = 0.f;
    float acc[NFL];
    #pragma unroll
    for (int j = 0; j < NFL; ++j) acc[j] = 0.f;

    int cnt = fill[n]; if (cnt > CAP) cnt = CAP;
    const unsigned short* cp = csr + ((unsigned)n << 6);
    int p = 0;
    for (; p + 4 <= cnt; p += 4){
      ushort4 s4 = *(const ushort4*)(cp + p);     // 8B broadcast
      unsigned sx = s4.x, sy = s4.y, sz = s4.z, sw = s4.w;
      float ax = alpha_s[sx * 4 + h];
      float ay = alpha_s[sy * 4 + h];
      float az = alpha_s[sz * 4 + h];
      float aw = alpha_s[sw * 4 + h];
      float vx[NFL], vy[NFL], vz[NFL], vw[NFL];
      ldrow<FIN, BF>(xg, sx, f0, vx);
      ldrow<FIN, BF>(xg, sy, f0, vy);
      ldrow<FIN, BF>(xg, sz, f0, vz);
      ldrow<FIN, BF>(xg, sw, f0, vw);
      float e0 = ax + adv; e0 = fmaxf(e0, 0.2f * e0); float w0 = __expf(e0);
      float e1 = ay + adv; e1 = fmaxf(e1, 0.2f * e1); float w1 = __expf(e1);
      float e2 = az + adv; e2 = fmaxf(e2, 0.2f * e2); float w2 = __expf(e2);
      float e3 = aw + adv; e3 = fmaxf(e3, 0.2f * e3); float w3 = __expf(e3);
      den += w0; den += w1; den += w2; den += w3;
      #pragma unroll
      for (int j = 0; j < NFL; ++j)
        acc[j] += w0 * vx[j] + w1 * vy[j] + w2 * vz[j] + w3 * vw[j];
    }
    for (; p < cnt; ++p){
      unsigned s = cp[p];
      float a = alpha_s[s * 4 + h];
      float v0[NFL];
      ldrow<FIN, BF>(xg, s, f0, v0);
      float e = a + adv; e = fmaxf(e, 0.2f * e); float wgt = __expf(e);
      den += wgt;
      #pragma unroll
      for (int j = 0; j < NFL; ++j) acc[j] += wgt * v0[j];
    }
    const float rh = (den > 0.f) ? (1.f / den) : 0.f;
    const int row = w * 4 + r;
    _Float16* yp = &ylds[row * STR + h * FIN + f0];
    #pragma unroll
    for (int j = 0; j < NFL; ++j) yp[j] = (_Float16)(acc[j] * rh);
  }
}

template<int FIN, int MODE>
__global__ __launch_bounds__(256) void k_aggrX(
    const void* __restrict__ xg,                 // [N, FIN] bf16 (or fp32 if MODE 0 && !flag)
    const float* __restrict__ alpha_s, const float* __restrict__ alpha_d,
    const int* __restrict__ fill, const unsigned short* __restrict__ csr,
    const _Float16* __restrict__ Wf,             // f16 B-frags, NT=4, KT=FIN/8
    const float* __restrict__ bias, void* __restrict__ out,
    const int* __restrict__ flag)
{
  const int K = 4 * FIN, KT = K / 32, STR = K + 8;
  __shared__ _Float16 ylds[16 * (4 * FIN + 8)];
  const int tid = threadIdx.x, w = tid >> 6, l = tid & 63;
  const int base = blockIdx.x * 16;               // N divisible by 16

  if (MODE == 0 && *flag == 0)
    aggr_phase1<FIN, false, STR>(xg, alpha_s, alpha_d, fill, csr, ylds, base, w, l);
  else
    aggr_phase1<FIN, true,  STR>(xg, alpha_s, alpha_d, fill, csr, ylds, base, w, l);
  __syncthreads();

  const int quad = l >> 4, m = l & 15;
  const int nt = w;                               // wave w -> output cols nt*16..
  f32x4 cacc = (f32x4)0.f;
  #pragma unroll
  for (int kt = 0; kt < KT; ++kt){
    f16x8 av = *(const f16x8*)&ylds[m * STR + kt * 32 + quad * 8];
    f16x8 bv = *(const f16x8*)(Wf + ((size_t)(nt * KT + kt) * 64 + l) * 8);
    cacc = __builtin_amdgcn_mfma_f32_16x16x32_f16(av, bv, cacc, 0, 0, 0);
  }
  const int c = nt * 16 + m;
  const float bs = bias[c];
  #pragma unroll
  for (int r2 = 0; r2 < 4; ++r2){
    int node = base + quad * 4 + r2;
    float v = cacc[r2] + bs;
    v = fmaxf(v, 0.1f * v);                       // post-layer leaky 0.1
    if (MODE == 0){
      ((unsigned short*)out)[(size_t)node * 64 + c] = f2bf(v);
    } else {
      if (*flag) ((unsigned short*)out)[(size_t)node * 64 + c] = f2bf(v);
      else       ((float*)out)[(size_t)node * 64 + c] = v;
    }
  }
}

// ---------------- launch ----------------

extern "C" void kernel_launch(void* const* d_in, const int* in_sizes, int n_in,
                              void* d_out, int out_size, void* d_ws, size_t ws_size,
                              hipStream_t stream)
{
  const void* x  = d_in[0];
  const int* ei  = (const int*)d_in[1];
  const int* src = ei;
  const int* dst = ei + N_EDGES;

  char* ws = (char*)d_ws;                      // footprint ~14.7 MB
  unsigned short* csr = (unsigned short*)(ws);             // [N*64] ushort padded CSR (6.4 MB)
  unsigned short* x2  = (unsigned short*)(ws + 6400000);   // [N,64] bf16 layer-1 out (6.4 MB)
  float* as_    = (float*)(ws + 12800000);     // [N,4]
  float* ad_    = (float*)(ws + 13600000);     // [N,4]
  int*   fill   = (int*)  (ws + 14400000);     // [N] scatter atomics = degree
  _Float16* Wb1f = (_Float16*)(ws + 14600000); // [32768] f16 stacked-W1 frags
  _Float16* Wb2f = (_Float16*)(ws + 14665536); // [16384] f16 stacked-W2 frags
  unsigned short* Bsd1f = (unsigned short*)(ws + 14698304);  // [2048] bf16
  unsigned short* Bsd2f = (unsigned short*)(ws + 14702400);  // [1024] bf16
  float* bc1    = (float*)(ws + 14704448);     // [64]
  float* bc2    = (float*)(ws + 14704704);     // [64]
  int*   flag   = (int*)  (ws + 14704960);     // dtype flag (1 = bf16)

  hipMemsetAsync(fill, 0, N_NODES * sizeof(int), stream);

  SetupPtrs S;
  S.W1 = d_in[2];  S.A1 = d_in[3];  S.aS1 = d_in[4];  S.aD1 = d_in[5];  S.b1 = d_in[6];
  S.W2 = d_in[7];  S.A2 = d_in[8];  S.aS2 = d_in[9];  S.aD2 = d_in[10]; S.b2 = d_in[11];
  S.x  = x;
  k_setup<<<205, 256, 0, stream>>>(S, Wb1f, Wb2f, Bsd1f, Bsd2f, bc1, bc2, flag);

  // scatter (782 blocks, 4 edges/thread) || layer-1 alpha (782 blocks)
  k_scatter_nodeA1<<<NB_SC4 + NB_NODE1, 256, 0, stream>>>(
      src, dst, fill, csr, x, Bsd1f, as_, ad_, flag);

  // layer 1: weighted-x aggregation + stacked-W1 MFMA -> x2 bf16
  k_aggrX<128, 0><<<N_NODES / 16, 256, 0, stream>>>(
      x, as_, ad_, fill, csr, Wb1f, bc1, x2, flag);

  // layer-2 alpha from x2 (always bf16)
  k_nodeA<64, false><<<NB_NODE1, 256, 0, stream>>>(x2, Bsd2f, as_, ad_, flag);

  // layer 2: aggregation + stacked-W2 MFMA -> final out
  k_aggrX<64, 1><<<N_NODES / 16, 256, 0, stream>>>(
      x2, as_, ad_, fill, csr, Wb2f, bc2, d_out, flag);
}

// Round 5
// 291.517 us; speedup vs baseline: 1.1049x; 1.0174x over previous
//
#include <hip/hip_runtime.h>

// GAT 2-layer fused pipeline for MI355X.
// N=50000 nodes, E=800000 edges, H=4 heads, C=64 channels, D=4 att dims.
// Inputs bf16 (runtime-detected, fp32 fallback); edge_index int32.
//
// Round-19 = r18 (297 us) + ONE change: 8-edge batches in aggr_phase1.
//   r18 counters: MfmaUtil 1.5%, VALUBusy 33%, HBM 29%, occ 52% -> latency-
//   bound gather with only 4 row-loads in flight. Doubling the batch to 8
//   (one ushort8 csr read, 8 staged x-rows + alphas, then consume) doubles
//   per-wave MLP. Same per-edge accumulation order -> numerics identical
//   (absmax 1.2207e-4).
//
// Structure (r16-r18): AGGREGATE-THEN-TRANSFORM.
//   sum_e w*(x_src@W) = (sum_e w*x_src)@W; per dst aggregate softmax-weighted
//   input features per head (lane layout: head = l>>4, sub = l&15, lane owns
//   FIN/16 features, ONE exp chain per edge), then stacked-weight MFMA
//   epilogue W'[h*Fin+f, c] = 0.25*W[f, h*64+c] (head-mean folded). No hmat.

#define N_NODES 50000
#define N_EDGES 800000
#define CAP 64        // padded-CSR per-node capacity (max degree ~40 here)
#define NB_SC4 782    // ceil(N_EDGES/1024) scatter blocks (4 edges/thread)
#define NB_NODE1 782  // ceil(N_NODES/64) nodeA blocks

typedef __attribute__((ext_vector_type(8))) short short8;       // 8 bf16
typedef __attribute__((ext_vector_type(8))) _Float16 f16x8;     // 8 fp16
typedef __attribute__((ext_vector_type(4))) float f32x4;
typedef __attribute__((ext_vector_type(8))) unsigned short ushort8;
typedef __attribute__((ext_vector_type(4))) unsigned short us4v;

__device__ __forceinline__ float bf2f(unsigned short u){
  return __uint_as_float(((unsigned int)u) << 16);
}
__device__ __forceinline__ unsigned short f2bf(float f){
  unsigned int u = __float_as_uint(f);
  u = (u + 0x7FFFu + ((u >> 16) & 1u)) >> 16;   // round-to-nearest-even
  return (unsigned short)u;
}
__device__ __forceinline__ float ldf(const void* p, int i, bool bf){
  return bf ? bf2f(((const unsigned short*)p)[i]) : ((const float*)p)[i];
}

// ---------------- weight prep (205 blocks) + dtype flag ----------------
// Blocks 0..127: W1' stacked-f16 frags; 128..191: W2'; 192..199: Bsd1 (bf16);
// 200..203: Bsd2; 204: bias copies + flag. Dtype self-detected per block.
// Stacked weight: W'[q, c] = 0.25*W[f, h*64+c], q = h*Fin+f  (head-mean folded).
// B-frag layout (mfma 16x16x32): Wf[((nt*KT+kt)*64+lane)*8+j] =
//   W'[q = kt*32+(lane>>4)*8+j][c = nt*16+(lane&15)], NT=4.
struct SetupPtrs {
  const void *W1, *A1, *aS1, *aD1, *b1, *W2, *A2, *aS2, *aD2, *b2, *x;
};

__global__ __launch_bounds__(256) void k_setup(SetupPtrs S,
    _Float16* __restrict__ Wb1f, _Float16* __restrict__ Wb2f,
    unsigned short* __restrict__ Bsd1f, unsigned short* __restrict__ Bsd2f,
    float* __restrict__ bc1, float* __restrict__ bc2,
    int* __restrict__ flag)
{
  __shared__ int sbf;
  const int tid = threadIdx.x;
  if (tid < 64){                                  // wave 0: dtype probe
    unsigned int w = ((const unsigned int*)S.x)[tid] & 0xFFFFu;
    unsigned int e = (w >> 7) & 0xFFu;
    bool hit = (e >= 100u && e <= 135u);
    unsigned long long m = __ballot(hit);
    if (tid == 0) sbf = (__popcll(m) > 40) ? 1 : 0;
  }
  __syncthreads();
  const bool bf = (sbf != 0);
  const int bw = blockIdx.x;
  if (bw < 128){                                  // W1' (K=512, KT=16): 32768 elems
    int t = bw * 256 + tid;
    int j = t & 7, lane = (t >> 3) & 63, kt = (t >> 9) & 15, nt = t >> 13;
    int q = kt * 32 + (lane >> 4) * 8 + j;        // 0..511
    int c = nt * 16 + (lane & 15);
    int h = q >> 7, f = q & 127;
    Wb1f[t] = (_Float16)(0.25f * ldf(S.W1, f * 256 + h * 64 + c, bf));
  } else if (bw < 192){                           // W2' (K=256, KT=8): 16384 elems
    int t = (bw - 128) * 256 + tid;
    int j = t & 7, lane = (t >> 3) & 63, kt = (t >> 9) & 7, nt = t >> 12;
    int q = kt * 32 + (lane >> 4) * 8 + j;        // 0..255
    int c = nt * 16 + (lane & 15);
    int h = q >> 6, f = q & 63;
    Wb2f[t] = (_Float16)(0.25f * ldf(S.W2, f * 256 + h * 64 + c, bf));
  } else if (bw < 200){                           // Bsd1 fragments: 2048 elems (kt<4)
    int t = (bw - 192) * 256 + tid;
    int j = t & 7, lane = (t >> 3) & 63, kt = t >> 9;
    int k = kt * 32 + (lane >> 4) * 8 + j;
    int c = lane & 15;
    float v = 0.f;
    if (c < 4){
      for (int dd = 0; dd < 4; ++dd)
        v += ldf(S.A1, k * 16 + c * 4 + dd, bf) * ldf(S.aS1, c * 4 + dd, bf);
    } else if (c < 8){
      int h = c - 4;
      for (int dd = 0; dd < 4; ++dd)
        v += ldf(S.A1, k * 16 + h * 4 + dd, bf) * ldf(S.aD1, h * 4 + dd, bf);
    }
    Bsd1f[t] = f2bf(v);
  } else if (bw < 204){                           // Bsd2 fragments: 1024 elems (kt<2)
    int t = (bw - 200) * 256 + tid;
    int j = t & 7, lane = (t >> 3) & 63, kt = t >> 9;
    int k = kt * 32 + (lane >> 4) * 8 + j;
    int c = lane & 15;
    float v = 0.f;
    if (c < 4){
      for (int dd = 0; dd < 4; ++dd)
        v += ldf(S.A2, k * 16 + c * 4 + dd, bf) * ldf(S.aS2, c * 4 + dd, bf);
    } else if (c < 8){
      int h = c - 4;
      for (int dd = 0; dd < 4; ++dd)
        v += ldf(S.A2, k * 16 + h * 4 + dd, bf) * ldf(S.aD2, h * 4 + dd, bf);
    }
    Bsd2f[t] = f2bf(v);
  } else {                                        // bias copies + flag
    if (tid < 64)       bc1[tid] = ldf(S.b1, tid, bf);
    else if (tid < 128) bc2[tid - 64] = ldf(S.b2, tid - 64, bf);
    else if (tid == 128) *flag = bf ? 1 : 0;
  }
}

// ---------------- alpha transform (r15 nodeM alpha path, W part stripped) ----------------

template<int F, bool DYN>
__device__ __forceinline__ void nodeA_body(int nblk, int tid,
    const void* __restrict__ xin_, const unsigned short* __restrict__ Bsdf,
    float* __restrict__ alpha_s, float* __restrict__ alpha_d,
    const int* __restrict__ flag)
{
  const int STR = F + 8;                   // row stride in ushorts (16B pad)
  const int KT  = F / 32;
  const int CH  = F / 8;
  __shared__ unsigned short xs[64 * (F + 8)];
  const int base = nblk * 64;
  bool bf = true;
  if (DYN) bf = (*flag != 0);
  for (int v = tid; v < 64 * CH; v += 256){
    int row = v / CH, c8 = v % CH;
    int node = base + row; if (node >= N_NODES) node = N_NODES - 1;
    size_t g = (size_t)node * F + c8 * 8;
    ushort8 u;
    if (!DYN || bf){
      u = *(const ushort8*)((const unsigned short*)xin_ + g);
    } else {
      const float* xf = (const float*)xin_ + g;
      float4 f0 = *(const float4*)xf, f1 = *(const float4*)(xf + 4);
      u[0]=f2bf(f0.x); u[1]=f2bf(f0.y); u[2]=f2bf(f0.z); u[3]=f2bf(f0.w);
      u[4]=f2bf(f1.x); u[5]=f2bf(f1.y); u[6]=f2bf(f1.z); u[7]=f2bf(f1.w);
    }
    *(ushort8*)&xs[row * STR + c8 * 8] = u;
  }
  __syncthreads();

  const int wave = tid >> 6, l = tid & 63;
  const int quad = l >> 4, m = l & 15;
  const int wbase = base + wave * 16;

  f32x4 aacc = (f32x4)0.f;
  #pragma unroll
  for (int kt = 0; kt < KT; ++kt){
    short8 af = *(const short8*)&xs[(wave * 16 + m) * STR + kt * 32 + quad * 8];
    short8 sdfrag = *(const short8*)(Bsdf + ((size_t)kt * 64 + l) * 8);
    aacc = __builtin_amdgcn_mfma_f32_16x16x32_bf16(af, sdfrag, aacc, 0, 0, 0);
  }
  if (m < 8){
    float* dstp = (m < 4) ? alpha_s : alpha_d;
    int hh = m & 3;
    #pragma unroll
    for (int r = 0; r < 4; ++r){
      int node = wbase + quad * 4 + r;
      if (node < N_NODES) dstp[node * 4 + hh] = aacc[r];
    }
  }
}

// ---------------- fused padded-CSR scatter (ushort, 4-edge ILP) + layer-1 alpha ----------------
// Blocks 0..781: scatter, 4 edges/thread for memory-level parallelism.
// Blocks 782..1563: nodeA1 (independent, overlaps scatter latency).

__global__ __launch_bounds__(256) void k_scatter_nodeA1(
    const int* __restrict__ src, const int* __restrict__ dst,
    int* __restrict__ fill, unsigned short* __restrict__ csr,
    const void* __restrict__ xin_, const unsigned short* __restrict__ Bsdf,
    float* __restrict__ alpha_s, float* __restrict__ alpha_d,
    const int* __restrict__ flag)
{
  const int b = blockIdx.x, tid = threadIdx.x;
  if (b < NB_SC4){
    const int ebase = b * 1024 + tid;
    int d[4], s[4];
    #pragma unroll
    for (int i = 0; i < 4; ++i){
      int e = ebase + i * 256;
      bool ok = (e < N_EDGES);
      d[i] = ok ? dst[e] : -1;
      s[i] = ok ? src[e] : 0;
    }
    #pragma unroll
    for (int i = 0; i < 4; ++i){
      if (d[i] >= 0){
        int r = atomicAdd(&fill[d[i]], 1);
        if (r < CAP) csr[((unsigned)d[i] << 6) + r] = (unsigned short)s[i];
      }
    }
    return;
  }
  nodeA_body<128, true>(b - NB_SC4, tid, xin_, Bsdf, alpha_s, alpha_d, flag);
}

// standalone layer-2 alpha kernel (x2 is always bf16)
template<int F, bool DYN>
__global__ __launch_bounds__(256) void k_nodeA(const void* __restrict__ xin_,
    const unsigned short* __restrict__ Bsdf,
    float* __restrict__ alpha_s, float* __restrict__ alpha_d,
    const int* __restrict__ flag)
{
  nodeA_body<F, DYN>(blockIdx.x, threadIdx.x, xin_, Bsdf, alpha_s, alpha_d, flag);
}

// ---------------- weighted-feature aggregation + stacked-W MFMA epilogue ----------------
// Block = 256 thr = 4 waves, 16 dst nodes (wave w owns nodes base+4w..base+4w+3).
// Phase 1 lane layout (r18): h = l>>4, sub = l&15; lane owns NFL = FIN/16
//   features. Per edge: ONE exp chain, NFL fma. r19: 8-edge batches for MLP.
// Phase 2: wave w computes output n-tile nt=w of [16 nodes]x[K=4*FIN]@W'[K,64]
//   via KT f16 MFMAs; + bias, leaky 0.1, store.
// MODE 0: layer 1 — x gather dtype per flag; out x2 bf16.
// MODE 1: layer 2 — x2 always bf16; out per flag (bf16 else fp32).

// load lane's NFL features of node s as fp32
template<int FIN, bool BF>
__device__ __forceinline__ void ldrow(const void* xg, unsigned s, int f0,
                                      float (&out)[FIN / 16])
{
  const int NFL = FIN / 16;
  if (BF){
    const unsigned short* p = (const unsigned short*)xg + (size_t)s * FIN + f0;
    if (NFL == 8){
      ushort8 u = *(const ushort8*)p;
      #pragma unroll
      for (int j = 0; j < NFL; ++j) out[j] = bf2f(u[j]);
    } else {
      us4v u = *(const us4v*)p;
      #pragma unroll
      for (int j = 0; j < NFL; ++j) out[j] = bf2f(u[j]);
    }
  } else {
    const float* p = (const float*)xg + (size_t)s * FIN + f0;
    #pragma unroll
    for (int j = 0; j < NFL; ++j) out[j] = p[j];
  }
}

template<int FIN, bool BF, int STR>
__device__ __forceinline__ void aggr_phase1(const void* __restrict__ xg,
    const float* __restrict__ alpha_s, const float* __restrict__ alpha_d,
    const int* __restrict__ fill, const unsigned short* __restrict__ csr,
    _Float16* __restrict__ ylds, int base, int w, int l)
{
  const int NFL = FIN / 16;                       // features per lane
  const int h = l >> 4, sub = l & 15, f0 = sub * NFL;
  #pragma unroll 1
  for (int r = 0; r < 4; ++r){
    const int n = base + w * 4 + r;
    const float adv = alpha_d[n * 4 + h];
    float den = 0.f;
    float acc[NFL];
    #pragma unroll
    for (int j = 0; j < NFL; ++j) acc[j] = 0.f;

    int cnt = fill[n]; if (cnt > CAP) cnt = CAP;
    const unsigned short* cp = csr + ((unsigned)n << 6);
    int p = 0;
    for (; p + 8 <= cnt; p += 8){                 // 8-edge batch: 8 rows in flight
      ushort8 s8 = *(const ushort8*)(cp + p);     // 16B broadcast
      float a[8];
      float v[8][NFL];
      #pragma unroll
      for (int i = 0; i < 8; ++i){
        unsigned s = s8[i];
        a[i] = alpha_s[s * 4 + h];
        ldrow<FIN, BF>(xg, s, f0, v[i]);
      }
      #pragma unroll
      for (int i = 0; i < 8; ++i){
        float e = a[i] + adv; e = fmaxf(e, 0.2f * e); float wt = __expf(e);
        den += wt;
        #pragma unroll
        for (int j = 0; j < NFL; ++j) acc[j] += wt * v[i][j];
      }
    }
    if (p + 4 <= cnt){                            // 4-edge batch
      ushort4 s4 = *(const ushort4*)(cp + p);
      unsigned sx = s4.x, sy = s4.y, sz = s4.z, sw = s4.w;
      float ax = alpha_s[sx * 4 + h];
      float ay = alpha_s[sy * 4 + h];
      float az = alpha_s[sz * 4 + h];
      float aw = alpha_s[sw * 4 + h];
      float vx[NFL], vy[NFL], vz[NFL], vw[NFL];
      ldrow<FIN, BF>(xg, sx, f0, vx);
      ldrow<FIN, BF>(xg, sy, f0, vy);
      ldrow<FIN, BF>(xg, sz, f0, vz);
      ldrow<FIN, BF>(xg, sw, f0, vw);
      float e0 = ax + adv; e0 = fmaxf(e0, 0.2f * e0); float w0 = __expf(e0);
      float e1 = ay + adv; e1 = fmaxf(e1, 0.2f * e1); float w1 = __expf(e1);
      float e2 = az + adv; e2 = fmaxf(e2, 0.2f * e2); float w2 = __expf(e2);
      float e3 = aw + adv; e3 = fmaxf(e3, 0.2f * e3); float w3 = __expf(e3);
      den += w0; den += w1; den += w2; den += w3;
      #pragma unroll
      for (int j = 0; j < NFL; ++j)
        acc[j] += w0 * vx[j] + w1 * vy[j] + w2 * vz[j] + w3 * vw[j];
      p += 4;
    }
    for (; p < cnt; ++p){                         // scalar tail (<4)
      unsigned s = cp[p];
      float a = alpha_s[s * 4 + h];
      float v0[NFL];
      ldrow<FIN, BF>(xg, s, f0, v0);
      float e = a + adv; e = fmaxf(e, 0.2f * e); float wgt = __expf(e);
      den += wgt;
      #pragma unroll
      for (int j = 0; j < NFL; ++j) acc[j] += wgt * v0[j];
    }
    const float rh = (den > 0.f) ? (1.f / den) : 0.f;
    const int row = w * 4 + r;
    _Float16* yp = &ylds[row * STR + h * FIN + f0];
    #pragma unroll
    for (int j = 0; j < NFL; ++j) yp[j] = (_Float16)(acc[j] * rh);
  }
}

template<int FIN, int MODE>
__global__ __launch_bounds__(256) void k_aggrX(
    const void* __restrict__ xg,                 // [N, FIN] bf16 (or fp32 if MODE 0 && !flag)
    const float* __restrict__ alpha_s, const float* __restrict__ alpha_d,
    const int* __restrict__ fill, const unsigned short* __restrict__ csr,
    const _Float16* __restrict__ Wf,             // f16 B-frags, NT=4, KT=FIN/8
    const float* __restrict__ bias, void* __restrict__ out,
    const int* __restrict__ flag)
{
  const int K = 4 * FIN, KT = K / 32, STR = K + 8;
  __shared__ _Float16 ylds[16 * (4 * FIN + 8)];
  const int tid = threadIdx.x, w = tid >> 6, l = tid & 63;
  const int base = blockIdx.x * 16;               // N divisible by 16

  if (MODE == 0 && *flag == 0)
    aggr_phase1<FIN, false, STR>(xg, alpha_s, alpha_d, fill, csr, ylds, base, w, l);
  else
    aggr_phase1<FIN, true,  STR>(xg, alpha_s, alpha_d, fill, csr, ylds, base, w, l);
  __syncthreads();

  const int quad = l >> 4, m = l & 15;
  const int nt = w;                               // wave w -> output cols nt*16..
  f32x4 cacc = (f32x4)0.f;
  #pragma unroll
  for (int kt = 0; kt < KT; ++kt){
    f16x8 av = *(const f16x8*)&ylds[m * STR + kt * 32 + quad * 8];
    f16x8 bv = *(const f16x8*)(Wf + ((size_t)(nt * KT + kt) * 64 + l) * 8);
    cacc = __builtin_amdgcn_mfma_f32_16x16x32_f16(av, bv, cacc, 0, 0, 0);
  }
  const int c = nt * 16 + m;
  const float bs = bias[c];
  #pragma unroll
  for (int r2 = 0; r2 < 4; ++r2){
    int node = base + quad * 4 + r2;
    float v = cacc[r2] + bs;
    v = fmaxf(v, 0.1f * v);                       // post-layer leaky 0.1
    if (MODE == 0){
      ((unsigned short*)out)[(size_t)node * 64 + c] = f2bf(v);
    } else {
      if (*flag) ((unsigned short*)out)[(size_t)node * 64 + c] = f2bf(v);
      else       ((float*)out)[(size_t)node * 64 + c] = v;
    }
  }
}

// ---------------- launch ----------------

extern "C" void kernel_launch(void* const* d_in, const int* in_sizes, int n_in,
                              void* d_out, int out_size, void* d_ws, size_t ws_size,
                              hipStream_t stream)
{
  const void* x  = d_in[0];
  const int* ei  = (const int*)d_in[1];
  const int* src = ei;
  const int* dst = ei + N_EDGES;

  char* ws = (char*)d_ws;                      // footprint ~14.7 MB
  unsigned short* csr = (unsigned short*)(ws);             // [N*64] ushort padded CSR (6.4 MB)
  unsigned short* x2  = (unsigned short*)(ws + 6400000);   // [N,64] bf16 layer-1 out (6.4 MB)
  float* as_    = (float*)(ws + 12800000);     // [N,4]
  float* ad_    = (float*)(ws + 13600000);     // [N,4]
  int*   fill   = (int*)  (ws + 14400000);     // [N] scatter atomics = degree
  _Float16* Wb1f = (_Float16*)(ws + 14600000); // [32768] f16 stacked-W1 frags
  _Float16* Wb2f = (_Float16*)(ws + 14665536); // [16384] f16 stacked-W2 frags
  unsigned short* Bsd1f = (unsigned short*)(ws + 14698304);  // [2048] bf16
  unsigned short* Bsd2f = (unsigned short*)(ws + 14702400);  // [1024] bf16
  float* bc1    = (float*)(ws + 14704448);     // [64]
  float* bc2    = (float*)(ws + 14704704);     // [64]
  int*   flag   = (int*)  (ws + 14704960);     // dtype flag (1 = bf16)

  hipMemsetAsync(fill, 0, N_NODES * sizeof(int), stream);

  SetupPtrs S;
  S.W1 = d_in[2];  S.A1 = d_in[3];  S.aS1 = d_in[4];  S.aD1 = d_in[5];  S.b1 = d_in[6];
  S.W2 = d_in[7];  S.A2 = d_in[8];  S.aS2 = d_in[9];  S.aD2 = d_in[10]; S.b2 = d_in[11];
  S.x  = x;
  k_setup<<<205, 256, 0, stream>>>(S, Wb1f, Wb2f, Bsd1f, Bsd2f, bc1, bc2, flag);

  // scatter (782 blocks, 4 edges/thread) || layer-1 alpha (782 blocks)
  k_scatter_nodeA1<<<NB_SC4 + NB_NODE1, 256, 0, stream>>>(
      src, dst, fill, csr, x, Bsd1f, as_, ad_, flag);

  // layer 1: weighted-x aggregation + stacked-W1 MFMA -> x2 bf16
  k_aggrX<128, 0><<<N_NODES / 16, 256, 0, stream>>>(
      x, as_, ad_, fill, csr, Wb1f, bc1, x2, flag);

  // layer-2 alpha from x2 (always bf16)
  k_nodeA<64, false><<<NB_NODE1, 256, 0, stream>>>(x2, Bsd2f, as_, ad_, flag);

  // layer 2: aggregation + stacked-W2 MFMA -> final out
  k_aggrX<64, 1><<<N_NODES / 16, 256, 0, stream>>>(
      x2, as_, ad_, fill, csr, Wb2f, bc2, d_out, flag);
}